// Round 1
// baseline (175.319 us; speedup 1.0000x reference)
//
#include <hip/hip_runtime.h>
#include <cmath>

// Problem constants (from setup_inputs): B=4, L=8192, H=128, P=64
constexpr int Bn = 4;
constexpr int Ln = 8192;
constexpr int Hn = 128;
constexpr int Pn = 64;
constexpr int Sc = 32;          // chunk length for the scan
constexpr int NC = Ln / Sc;     // 256 chunks
constexpr int ROWS = 8;         // rows per block in the GEMM-ish kernels

// transition matrix M(p) for the implicit LinOSS update
__device__ __forceinline__ void make_M(float A, float st,
    float& m11, float& m12, float& m21, float& m22) {
  float s2A   = st * st * A;
  float schur = 1.0f / (1.0f + s2A);
  m11 = 1.0f - s2A * schur;
  m12 = -st * A * schur;
  m21 = st * schur;
  m22 = schur;
}

// ---------------------------------------------------------------- Bu = stack(u@Br^T, u@Bi^T)
__global__ __launch_bounds__(256) void bu_kernel(
    const float* __restrict__ u, const float* __restrict__ Br,
    const float* __restrict__ Bi, float* __restrict__ Bu) {
  __shared__ float us[ROWS][Hn];
  const int row0 = blockIdx.x * ROWS;
  const int t = threadIdx.x;
  for (int i = t; i < ROWS * Hn; i += 256)
    us[i / Hn][i % Hn] = u[(size_t)row0 * Hn + i];
  __syncthreads();

  const int pc = t & 127;
  const int c = pc >> 6;        // 0 = real, 1 = imag
  const int p = pc & 63;
  const int rhalf = t >> 7;     // 0 or 1
  const float* __restrict__ Bm = c ? Bi : Br;

  float acc[ROWS / 2];
  #pragma unroll
  for (int i = 0; i < ROWS / 2; ++i) acc[i] = 0.f;

  #pragma unroll 16
  for (int h = 0; h < Hn; ++h) {
    float bv = Bm[p * Hn + h];
    #pragma unroll
    for (int i = 0; i < ROWS / 2; ++i)
      acc[i] = fmaf(us[rhalf + 2 * i][h], bv, acc[i]);
  }
  #pragma unroll
  for (int i = 0; i < ROWS / 2; ++i) {
    int r = rhalf + 2 * i;
    Bu[((size_t)(row0 + r) * Pn + p) * 2 + c] = acc[i];
  }
}

// ---------------------------------------------------------------- pass A: per-chunk local scan
__global__ __launch_bounds__(256) void scanA_kernel(
    const float* __restrict__ Bu, const float* __restrict__ Ad,
    const float* __restrict__ steps, float2* __restrict__ carry) {
  const int tid = blockIdx.x * 256 + threadIdx.x;
  const int c = tid & 1;
  const int p = (tid >> 1) & 63;
  const int chunk = (tid >> 7) & (NC - 1);
  const int b = tid >> 15;      // NC=256 -> 8 bits chunk + 7 bits (p,c)

  const float A  = fmaxf(Ad[p], 0.0f);
  const float st = 1.0f / (1.0f + expf(-steps[p]));
  float m11, m12, m21, m22;
  make_M(A, st, m11, m12, m21, m22);
  const float f1 = m11 * st, f2 = m21 * st;

  const float* __restrict__ src =
      Bu + ((size_t)(b * Ln + chunk * Sc) * Pn + p) * 2 + c;

  float z = 0.f, x = 0.f;
  #pragma unroll 8
  for (int s = 0; s < Sc; ++s) {
    float bu = src[(size_t)s * (Pn * 2)];
    float zn = fmaf(m11, z, fmaf(m12, x, f1 * bu));
    float xn = fmaf(m21, z, fmaf(m22, x, f2 * bu));
    z = zn; x = xn;
  }
  carry[tid] = make_float2(z, x);
}

// ---------------------------------------------------------------- pass B: propagate carries across chunks
__global__ __launch_bounds__(256) void scanB_kernel(
    const float* __restrict__ Ad, const float* __restrict__ steps,
    float2* __restrict__ carry) {
  const int tid = blockIdx.x * 256 + threadIdx.x;  // 0..511
  const int c = tid & 1;
  const int p = (tid >> 1) & 63;
  const int b = tid >> 7;
  (void)c;

  const float A  = fmaxf(Ad[p], 0.0f);
  const float st = 1.0f / (1.0f + expf(-steps[p]));
  float m11, m12, m21, m22;
  make_M(A, st, m11, m12, m21, m22);

  // M^Sc by repeated squaring (Sc = 32 -> 5 squarings)
  float a = m11, bq = m12, cq = m21, d = m22;
  #pragma unroll
  for (int i = 0; i < 5; ++i) {
    float na = a * a + bq * cq;
    float nb = a * bq + bq * d;
    float nc = cq * a + d * cq;
    float nd = cq * bq + d * d;
    a = na; bq = nb; cq = nc; d = nd;
  }

  float z = 0.f, x = 0.f;
  #pragma unroll 4
  for (int j = 0; j < NC; ++j) {
    size_t idx = ((size_t)(b * NC + j) * Pn + p) * 2 + c;
    float2 loc = carry[idx];
    float zn = fmaf(a,  z, fmaf(bq, x, loc.x));
    float xn = fmaf(cq, z, fmaf(d,  x, loc.y));
    carry[idx] = make_float2(z, x);   // exclusive prefix = chunk's true initial state
    z = zn; x = xn;
  }
}

// ---------------------------------------------------------------- pass C: rescan with true init, emit x
__global__ __launch_bounds__(256) void scanC_kernel(
    const float* __restrict__ Bu, const float* __restrict__ Ad,
    const float* __restrict__ steps, const float2* __restrict__ carry,
    float* __restrict__ ys) {
  const int tid = blockIdx.x * 256 + threadIdx.x;
  const int c = tid & 1;
  const int p = (tid >> 1) & 63;
  const int chunk = (tid >> 7) & (NC - 1);
  const int b = tid >> 15;

  const float A  = fmaxf(Ad[p], 0.0f);
  const float st = 1.0f / (1.0f + expf(-steps[p]));
  float m11, m12, m21, m22;
  make_M(A, st, m11, m12, m21, m22);
  const float f1 = m11 * st, f2 = m21 * st;

  const size_t base = ((size_t)(b * Ln + chunk * Sc) * Pn + p) * 2 + c;
  const float* __restrict__ src = Bu + base;
  float* __restrict__ dst = ys + base;

  float2 init = carry[tid];
  float z = init.x, x = init.y;
  #pragma unroll 8
  for (int s = 0; s < Sc; ++s) {
    float bu = src[(size_t)s * (Pn * 2)];
    float zn = fmaf(m11, z, fmaf(m12, x, f1 * bu));
    float xn = fmaf(m21, z, fmaf(m22, x, f2 * bu));
    z = zn; x = xn;
    dst[(size_t)s * (Pn * 2)] = x;
  }
}

// ---------------------------------------------------------------- out = ys_r@Cr^T - ys_i@Ci^T + u*D
__global__ __launch_bounds__(256) void out_kernel(
    const float* __restrict__ ys, const float* __restrict__ u,
    const float* __restrict__ Cr, const float* __restrict__ Ci,
    const float* __restrict__ Dv, float* __restrict__ out) {
  __shared__ float yl[ROWS][Pn * 2];
  const int row0 = blockIdx.x * ROWS;
  const int t = threadIdx.x;
  for (int i = t; i < ROWS * Pn * 2; i += 256)
    yl[i / (Pn * 2)][i % (Pn * 2)] = ys[(size_t)row0 * (Pn * 2) + i];
  __syncthreads();

  const int h = t & 127;
  const int rhalf = t >> 7;

  float acc[ROWS / 2];
  #pragma unroll
  for (int i = 0; i < ROWS / 2; ++i) acc[i] = 0.f;

  #pragma unroll 8
  for (int p = 0; p < Pn; ++p) {
    float cr = Cr[h * Pn + p];
    float ci = Ci[h * Pn + p];
    #pragma unroll
    for (int i = 0; i < ROWS / 2; ++i) {
      int r = rhalf + 2 * i;
      acc[i] = fmaf(yl[r][2 * p], cr, acc[i]);
      acc[i] = fmaf(yl[r][2 * p + 1], -ci, acc[i]);
    }
  }
  const float dv = Dv[h];
  #pragma unroll
  for (int i = 0; i < ROWS / 2; ++i) {
    int r = rhalf + 2 * i;
    size_t o = (size_t)(row0 + r) * Hn + h;
    out[o] = fmaf(u[o], dv, acc[i]);
  }
}

extern "C" void kernel_launch(void* const* d_in, const int* in_sizes, int n_in,
                              void* d_out, int out_size, void* d_ws, size_t ws_size,
                              hipStream_t stream) {
  const float* u     = (const float*)d_in[0];
  const float* Ad    = (const float*)d_in[1];
  const float* Br    = (const float*)d_in[2];
  const float* Bi    = (const float*)d_in[3];
  const float* Cr    = (const float*)d_in[4];
  const float* Ci    = (const float*)d_in[5];
  const float* Dv    = (const float*)d_in[6];
  const float* steps = (const float*)d_in[7];
  float* out = (float*)d_out;

  // workspace layout (floats): Bu [B*L*P*2] | ys [B*L*P*2] | carry [B*NC*P*2 float2]
  float*  Bu    = (float*)d_ws;
  float*  ys    = Bu + (size_t)Bn * Ln * Pn * 2;
  float2* carry = (float2*)(ys + (size_t)Bn * Ln * Pn * 2);

  const int nrow = Bn * Ln;                 // 32768
  const int scan_threads = Bn * NC * Pn * 2; // 131072

  bu_kernel  <<<nrow / ROWS,        256, 0, stream>>>(u, Br, Bi, Bu);
  scanA_kernel<<<scan_threads / 256, 256, 0, stream>>>(Bu, Ad, steps, carry);
  scanB_kernel<<<(Bn * Pn * 2) / 256, 256, 0, stream>>>(Ad, steps, carry);
  scanC_kernel<<<scan_threads / 256, 256, 0, stream>>>(Bu, Ad, steps, carry, ys);
  out_kernel <<<nrow / ROWS,        256, 0, stream>>>(ys, u, Cr, Ci, Dv, out);
}

// Round 2
// 103.908 us; speedup vs baseline: 1.6873x; 1.6873x over previous
//
#include <hip/hip_runtime.h>
#include <cmath>

// Problem constants (from setup_inputs): B=4, L=8192, H=128, P=64
constexpr int Bn = 4;
constexpr int Ln = 8192;
constexpr int Hn = 128;
constexpr int Pn = 64;
constexpr int Sc = 32;          // chunk length for the scan
constexpr int NC = Ln / Sc;     // 256 chunks
constexpr int RB = 64;          // rows per block in GEMM kernels

typedef float f4 __attribute__((ext_vector_type(4)));

// transition matrix M(p) for the implicit LinOSS update
__device__ __forceinline__ void make_M(float A, float st,
    float& m11, float& m12, float& m21, float& m22) {
  float s2A   = st * st * A;
  float schur = 1.0f / (1.0f + s2A);
  m11 = 1.0f - s2A * schur;
  m12 = -st * A * schur;
  m21 = st * schur;
  m22 = schur;
}

// ------------------------------------------------- prep: transpose/interleave weights
// WbT[h][k] = (k&1 ? Bi : Br)[k>>1][h]          (so Bu[r][k] = sum_h u[r][h]*WbT[h][k])
// WcT[k][h] = (k&1 ? -Ci : Cr)[h][k>>1]         (so out[r][h] = sum_k ys[r][k]*WcT[k][h])
__global__ __launch_bounds__(256) void prep_kernel(
    const float* __restrict__ Br, const float* __restrict__ Bi,
    const float* __restrict__ Cr, const float* __restrict__ Ci,
    float* __restrict__ WbT, float* __restrict__ WcT) {
  int tid = blockIdx.x * 256 + threadIdx.x;
  if (tid < Hn * Hn) {
    int h = tid >> 7, k = tid & 127, p = k >> 1;
    WbT[tid] = (k & 1) ? Bi[p * Hn + h] : Br[p * Hn + h];
  } else {
    int i = tid - Hn * Hn;
    int k = i >> 7, h = i & 127, p = k >> 1;
    WcT[i] = (k & 1) ? -Ci[h * Pn + p] : Cr[h * Pn + p];
  }
}

// ------------------------------------------------- Bu = u @ WbT   (32768x128 @ 128x128)
__global__ __launch_bounds__(256) void bu2_kernel(
    const float* __restrict__ u, const float* __restrict__ WbT,
    float* __restrict__ Bu) {
  __shared__ float us[RB][Hn];          // broadcast-read -> no pad needed
  const int t = threadIdx.x;
  const size_t row0 = (size_t)blockIdx.x * RB;

  const f4* __restrict__ u4 = (const f4*)(u + row0 * Hn);
  f4* usv = (f4*)us;
  for (int i = t; i < RB * Hn / 4; i += 256) usv[i] = u4[i];
  __syncthreads();

  const int tc = t & 31;                // cols 4tc..4tc+3
  const int tr = t >> 5;                // rows tr*8 .. tr*8+7
  const f4* __restrict__ W4 = (const f4*)WbT;

  f4 acc[8];
  #pragma unroll
  for (int j = 0; j < 8; ++j) acc[j] = (f4)0.f;

  #pragma unroll 4
  for (int h4 = 0; h4 < Hn; h4 += 4) {
    f4 w[4];
    #pragma unroll
    for (int jj = 0; jj < 4; ++jj) w[jj] = W4[(h4 + jj) * (Hn / 4) + tc];
    #pragma unroll
    for (int j = 0; j < 8; ++j) {
      f4 uv = *(const f4*)&us[tr * 8 + j][h4];
      #pragma unroll
      for (int jj = 0; jj < 4; ++jj) acc[j] += uv[jj] * w[jj];
    }
  }

  f4* __restrict__ Bu4 = (f4*)Bu;
  #pragma unroll
  for (int j = 0; j < 8; ++j)
    Bu4[(row0 + tr * 8 + j) * (Hn / 4) + tc] = acc[j];
}

// ------------------------------------------------- pass A: per-chunk local scan
__global__ __launch_bounds__(256) void scanA_kernel(
    const float* __restrict__ Bu, const float* __restrict__ Ad,
    const float* __restrict__ steps, float2* __restrict__ carry) {
  const int tid = blockIdx.x * 256 + threadIdx.x;
  const int c = tid & 1;
  const int p = (tid >> 1) & 63;
  const int chunk = (tid >> 7) & (NC - 1);
  const int b = tid >> 15;

  const float A  = fmaxf(Ad[p], 0.0f);
  const float st = 1.0f / (1.0f + expf(-steps[p]));
  float m11, m12, m21, m22;
  make_M(A, st, m11, m12, m21, m22);
  const float f1 = m11 * st, f2 = m21 * st;

  const float* __restrict__ src =
      Bu + ((size_t)(b * Ln + chunk * Sc) * Pn + p) * 2 + c;

  float z = 0.f, x = 0.f;
  #pragma unroll 8
  for (int s = 0; s < Sc; ++s) {
    float bu = src[(size_t)s * (Pn * 2)];
    float zn = fmaf(m11, z, fmaf(m12, x, f1 * bu));
    float xn = fmaf(m21, z, fmaf(m22, x, f2 * bu));
    z = zn; x = xn;
  }
  carry[tid] = make_float2(z, x);
}

// ------------------------------------------------- pass B: propagate carries across chunks
__global__ __launch_bounds__(256) void scanB_kernel(
    const float* __restrict__ Ad, const float* __restrict__ steps,
    float2* __restrict__ carry) {
  const int tid = blockIdx.x * 256 + threadIdx.x;  // 0..511
  const int c = tid & 1;
  const int p = (tid >> 1) & 63;
  const int b = tid >> 7;
  (void)c;

  const float A  = fmaxf(Ad[p], 0.0f);
  const float st = 1.0f / (1.0f + expf(-steps[p]));
  float m11, m12, m21, m22;
  make_M(A, st, m11, m12, m21, m22);

  // M^Sc by repeated squaring (Sc = 32 -> 5 squarings)
  float a = m11, bq = m12, cq = m21, d = m22;
  #pragma unroll
  for (int i = 0; i < 5; ++i) {
    float na = a * a + bq * cq;
    float nb = a * bq + bq * d;
    float nc = cq * a + d * cq;
    float nd = cq * bq + d * d;
    a = na; bq = nb; cq = nc; d = nd;
  }

  float z = 0.f, x = 0.f;
  #pragma unroll 4
  for (int j = 0; j < NC; ++j) {
    size_t idx = ((size_t)(b * NC + j) * Pn + p) * 2 + c;
    float2 loc = carry[idx];
    float zn = fmaf(a,  z, fmaf(bq, x, loc.x));
    float xn = fmaf(cq, z, fmaf(d,  x, loc.y));
    carry[idx] = make_float2(z, x);   // exclusive prefix = chunk's true initial state
    z = zn; x = xn;
  }
}

// ------------------------------------------------- pass C: rescan with true init, emit x
__global__ __launch_bounds__(256) void scanC_kernel(
    const float* __restrict__ Bu, const float* __restrict__ Ad,
    const float* __restrict__ steps, const float2* __restrict__ carry,
    float* __restrict__ ys) {
  const int tid = blockIdx.x * 256 + threadIdx.x;
  const int c = tid & 1;
  const int p = (tid >> 1) & 63;
  const int chunk = (tid >> 7) & (NC - 1);
  const int b = tid >> 15;

  const float A  = fmaxf(Ad[p], 0.0f);
  const float st = 1.0f / (1.0f + expf(-steps[p]));
  float m11, m12, m21, m22;
  make_M(A, st, m11, m12, m21, m22);
  const float f1 = m11 * st, f2 = m21 * st;

  const size_t base = ((size_t)(b * Ln + chunk * Sc) * Pn + p) * 2 + c;
  const float* __restrict__ src = Bu + base;
  float* __restrict__ dst = ys + base;

  float2 init = carry[tid];
  float z = init.x, x = init.y;
  #pragma unroll 8
  for (int s = 0; s < Sc; ++s) {
    float bu = src[(size_t)s * (Pn * 2)];
    float zn = fmaf(m11, z, fmaf(m12, x, f1 * bu));
    float xn = fmaf(m21, z, fmaf(m22, x, f2 * bu));
    z = zn; x = xn;
    dst[(size_t)s * (Pn * 2)] = x;
  }
}

// ------------------------------------------------- out = ys @ WcT + u*D
__global__ __launch_bounds__(256) void out2_kernel(
    const float* __restrict__ ys, const float* __restrict__ u,
    const float* __restrict__ WcT, const float* __restrict__ Dv,
    float* __restrict__ out) {
  __shared__ float yl[RB][Hn];
  const int t = threadIdx.x;
  const size_t row0 = (size_t)blockIdx.x * RB;

  const f4* __restrict__ y4 = (const f4*)(ys + row0 * Hn);
  f4* ylv = (f4*)yl;
  for (int i = t; i < RB * Hn / 4; i += 256) ylv[i] = y4[i];
  __syncthreads();

  const int tc = t & 31;                // out cols 4tc..4tc+3 (h)
  const int tr = t >> 5;                // rows tr*8 .. tr*8+7
  const f4* __restrict__ W4 = (const f4*)WcT;

  f4 acc[8];
  #pragma unroll
  for (int j = 0; j < 8; ++j) acc[j] = (f4)0.f;

  #pragma unroll 4
  for (int k4 = 0; k4 < Hn; k4 += 4) {
    f4 w[4];
    #pragma unroll
    for (int jj = 0; jj < 4; ++jj) w[jj] = W4[(k4 + jj) * (Hn / 4) + tc];
    #pragma unroll
    for (int j = 0; j < 8; ++j) {
      f4 yv = *(const f4*)&yl[tr * 8 + j][k4];
      #pragma unroll
      for (int jj = 0; jj < 4; ++jj) acc[j] += yv[jj] * w[jj];
    }
  }

  const f4 dv = ((const f4*)Dv)[tc];
  const f4* __restrict__ u4 = (const f4*)u;
  f4* __restrict__ out4 = (f4*)out;
  #pragma unroll
  for (int j = 0; j < 8; ++j) {
    size_t o = (row0 + tr * 8 + j) * (Hn / 4) + tc;
    f4 uv = u4[o];
    out4[o] = acc[j] + uv * dv;
  }
}

extern "C" void kernel_launch(void* const* d_in, const int* in_sizes, int n_in,
                              void* d_out, int out_size, void* d_ws, size_t ws_size,
                              hipStream_t stream) {
  const float* u     = (const float*)d_in[0];
  const float* Ad    = (const float*)d_in[1];
  const float* Br    = (const float*)d_in[2];
  const float* Bi    = (const float*)d_in[3];
  const float* Cr    = (const float*)d_in[4];
  const float* Ci    = (const float*)d_in[5];
  const float* Dv    = (const float*)d_in[6];
  const float* steps = (const float*)d_in[7];
  float* out = (float*)d_out;

  // workspace (floats): Bu [4M] | ys [4M] | carry [256K f2] | WbT [16K] | WcT [16K]
  float*  Bu    = (float*)d_ws;
  float*  ys    = Bu + (size_t)Bn * Ln * Pn * 2;
  float2* carry = (float2*)(ys + (size_t)Bn * Ln * Pn * 2);
  float*  WbT   = (float*)(carry + (size_t)Bn * NC * Pn * 2);
  float*  WcT   = WbT + Hn * Hn;

  const int nrow = Bn * Ln;                  // 32768
  const int scan_threads = Bn * NC * Pn * 2; // 131072

  prep_kernel <<<2 * Hn * Hn / 256,  256, 0, stream>>>(Br, Bi, Cr, Ci, WbT, WcT);
  bu2_kernel  <<<nrow / RB,          256, 0, stream>>>(u, WbT, Bu);
  scanA_kernel<<<scan_threads / 256, 256, 0, stream>>>(Bu, Ad, steps, carry);
  scanB_kernel<<<(Bn * Pn * 2) / 256, 256, 0, stream>>>(Ad, steps, carry);
  scanC_kernel<<<scan_threads / 256, 256, 0, stream>>>(Bu, Ad, steps, carry, ys);
  out2_kernel <<<nrow / RB,          256, 0, stream>>>(ys, u, WcT, Dv, out);
}

// Round 3
// 63.266 us; speedup vs baseline: 2.7711x; 1.6424x over previous
//
#include <hip/hip_runtime.h>
#include <cmath>

// Problem constants: B=4, L=8192, H=128, P=64
constexpr int Bn = 4;
constexpr int Ln = 8192;
constexpr int Hn = 128;
constexpr int Pn = 64;
constexpr int Kn = 128;         // 2*P interleaved (k = 2p+c)
constexpr int Sc = 64;          // chunk length (rows per block)
constexpr int NC = Ln / Sc;     // 128 chunks per batch

typedef float f4 __attribute__((ext_vector_type(4)));

__device__ __forceinline__ void make_M(float A, float st,
    float& m11, float& m12, float& m21, float& m22) {
  float s2A   = st * st * A;
  float schur = 1.0f / (1.0f + s2A);
  m11 = 1.0f - s2A * schur;
  m12 = -st * A * schur;
  m21 = st * schur;
  m22 = schur;
}

// ------------------------------------------------- prep: transpose/interleave weights
// WbT[h][k] = (k&1 ? Bi : Br)[k>>1][h]   (Bu[r][k] = sum_h u[r][h]*WbT[h][k])
// WcT[k][h] = (k&1 ? -Ci : Cr)[h][k>>1]  (out[r][h] = sum_k ys[r][k]*WcT[k][h])
__global__ __launch_bounds__(256) void prep_kernel(
    const float* __restrict__ Br, const float* __restrict__ Bi,
    const float* __restrict__ Cr, const float* __restrict__ Ci,
    float* __restrict__ WbT, float* __restrict__ WcT) {
  int tid = blockIdx.x * 256 + threadIdx.x;
  if (tid < Hn * Kn) {
    int h = tid >> 7, k = tid & 127, p = k >> 1;
    WbT[tid] = (k & 1) ? Bi[p * Hn + h] : Br[p * Hn + h];
  } else {
    int i = tid - Hn * Kn;
    int k = i >> 7, h = i & 127, p = k >> 1;
    WcT[i] = (k & 1) ? -Ci[h * Pn + p] : Cr[h * Pn + p];
  }
}

// ------------------------------------------------- K1: Bu GEMM (LDS) + local chunk scan -> carry
__global__ __launch_bounds__(256) void k1_bu_scan(
    const float* __restrict__ u, const float* __restrict__ WbT,
    const float* __restrict__ Ad, const float* __restrict__ steps,
    float2* __restrict__ carry) {
  __shared__ float us[Sc][Hn];
  __shared__ float bu[Sc][Kn];
  const int t = threadIdx.x;
  const int b = blockIdx.x >> 7;
  const int chunk = blockIdx.x & (NC - 1);
  const size_t row0 = (size_t)b * Ln + (size_t)chunk * Sc;

  // stage u rows
  const f4* __restrict__ u4 = (const f4*)(u + row0 * Hn);
  f4* usv = (f4*)us;
  #pragma unroll
  for (int i = 0; i < Sc * Hn / 4 / 256; ++i) usv[t + i * 256] = u4[t + i * 256];
  __syncthreads();

  // GEMM: 64x128 @ 128x128 -> bu (LDS)
  const int tc = t & 31;   // k-cols 4tc..4tc+3
  const int tr = t >> 5;   // rows tr*8..tr*8+7
  const f4* __restrict__ W4 = (const f4*)WbT;
  f4 acc[8];
  #pragma unroll
  for (int j = 0; j < 8; ++j) acc[j] = (f4)0.f;
  #pragma unroll 4
  for (int h4 = 0; h4 < Hn; h4 += 4) {
    f4 w[4];
    #pragma unroll
    for (int jj = 0; jj < 4; ++jj) w[jj] = W4[(h4 + jj) * (Kn / 4) + tc];
    #pragma unroll
    for (int j = 0; j < 8; ++j) {
      f4 uv = *(const f4*)&us[tr * 8 + j][h4];
      #pragma unroll
      for (int jj = 0; jj < 4; ++jj) acc[j] += uv[jj] * w[jj];
    }
  }
  #pragma unroll
  for (int j = 0; j < 8; ++j) *(f4*)&bu[tr * 8 + j][4 * tc] = acc[j];
  __syncthreads();

  // local scan over Sc steps (threads 0..127, one per k)
  if (t < Kn) {
    const int p = t >> 1;
    const float A  = fmaxf(Ad[p], 0.0f);
    const float st = 1.0f / (1.0f + expf(-steps[p]));
    float m11, m12, m21, m22;
    make_M(A, st, m11, m12, m21, m22);
    const float f1 = m11 * st, f2 = m21 * st;
    float z = 0.f, x = 0.f;
    #pragma unroll 8
    for (int s = 0; s < Sc; ++s) {
      float bv = bu[s][t];
      float zn = fmaf(m11, z, fmaf(m12, x, f1 * bv));
      float xn = fmaf(m21, z, fmaf(m22, x, f2 * bv));
      z = zn; x = xn;
    }
    carry[((size_t)b * NC + chunk) * Kn + t] = make_float2(z, x);
  }
}

// ------------------------------------------------- K2: wave-parallel carry propagation
// one wave per series (b,k); lane i folds chunks {2i,2i+1}; shfl-scan of affine maps.
__global__ __launch_bounds__(256) void k2_propagate(
    const float* __restrict__ Ad, const float* __restrict__ steps,
    float2* __restrict__ carry) {
  const int wave = threadIdx.x >> 6;
  const int lane = threadIdx.x & 63;
  const int series = blockIdx.x * 4 + wave;        // 0..511
  const int b = series >> 7;
  const int k = series & 127;
  const int p = k >> 1;

  const float A  = fmaxf(Ad[p], 0.0f);
  const float st = 1.0f / (1.0f + expf(-steps[p]));
  float m11, m12, m21, m22;
  make_M(A, st, m11, m12, m21, m22);
  // A_c = M^Sc (Sc=64 -> 6 squarings)
  float ca = m11, cb = m12, cc = m21, cd = m22;
  #pragma unroll
  for (int i = 0; i < 6; ++i) {
    float na = ca * ca + cb * cc;
    float nb = ca * cb + cb * cd;
    float nc = cc * ca + cd * cc;
    float nd = cc * cb + cd * cd;
    ca = na; cb = nb; cc = nc; cd = nd;
  }

  const size_t base = ((size_t)b * NC) * Kn + k;
  float2 c0 = carry[base + (size_t)(2 * lane) * Kn];
  float2 c1 = carry[base + (size_t)(2 * lane + 1) * Kn];

  // lane-local fold: chunk 2i then 2i+1
  float Aa = ca * ca + cb * cc;
  float Ab = ca * cb + cb * cd;
  float Ac = cc * ca + cd * cc;
  float Adl = cc * cb + cd * cd;
  float bz = ca * c0.x + cb * c0.y + c1.x;
  float bx = cc * c0.x + cd * c0.y + c1.y;

  // inclusive scan: (A,b) <- (A,b) ∘ (A_lo,b_lo)
  #pragma unroll
  for (int d = 1; d < 64; d <<= 1) {
    float oAa = __shfl_up(Aa, d), oAb = __shfl_up(Ab, d);
    float oAc = __shfl_up(Ac, d), oAd = __shfl_up(Adl, d);
    float obz = __shfl_up(bz, d), obx = __shfl_up(bx, d);
    if (lane >= d) {
      float nbz = Aa * obz + Ab * obx + bz;
      float nbx = Ac * obz + Adl * obx + bx;
      float nAa = Aa * oAa + Ab * oAc;
      float nAb = Aa * oAb + Ab * oAd;
      float nAc = Ac * oAa + Adl * oAc;
      float nAd = Ac * oAb + Adl * oAd;
      Aa = nAa; Ab = nAb; Ac = nAc; Adl = nAd; bz = nbz; bx = nbx;
    }
  }

  // exclusive prefix b-component (init state is 0, so only b matters)
  float ebz = __shfl_up(bz, 1);
  float ebx = __shfl_up(bx, 1);
  if (lane == 0) { ebz = 0.f; ebx = 0.f; }

  // init for chunk 2i, and for chunk 2i+1 = A_c*init + c0
  carry[base + (size_t)(2 * lane) * Kn]     = make_float2(ebz, ebx);
  carry[base + (size_t)(2 * lane + 1) * Kn] =
      make_float2(ca * ebz + cb * ebx + c0.x, cc * ebz + cd * ebx + c0.y);
}

// ------------------------------------------------- K3: recompute Bu GEMM + rescan + out GEMM + residual
__global__ __launch_bounds__(256) void k3_scan_out(
    const float* __restrict__ u, const float* __restrict__ WbT,
    const float* __restrict__ WcT, const float* __restrict__ Dv,
    const float* __restrict__ Ad, const float* __restrict__ steps,
    const float2* __restrict__ carry, float* __restrict__ out) {
  __shared__ float us[Sc][Hn];
  __shared__ float bu[Sc][Kn];     // Bu, overwritten with ys in-place
  const int t = threadIdx.x;
  const int b = blockIdx.x >> 7;
  const int chunk = blockIdx.x & (NC - 1);
  const size_t row0 = (size_t)b * Ln + (size_t)chunk * Sc;

  const f4* __restrict__ u4 = (const f4*)(u + row0 * Hn);
  f4* usv = (f4*)us;
  #pragma unroll
  for (int i = 0; i < Sc * Hn / 4 / 256; ++i) usv[t + i * 256] = u4[t + i * 256];
  __syncthreads();

  const int tc = t & 31;
  const int tr = t >> 5;
  {
    const f4* __restrict__ W4 = (const f4*)WbT;
    f4 acc[8];
    #pragma unroll
    for (int j = 0; j < 8; ++j) acc[j] = (f4)0.f;
    #pragma unroll 4
    for (int h4 = 0; h4 < Hn; h4 += 4) {
      f4 w[4];
      #pragma unroll
      for (int jj = 0; jj < 4; ++jj) w[jj] = W4[(h4 + jj) * (Kn / 4) + tc];
      #pragma unroll
      for (int j = 0; j < 8; ++j) {
        f4 uv = *(const f4*)&us[tr * 8 + j][h4];
        #pragma unroll
        for (int jj = 0; jj < 4; ++jj) acc[j] += uv[jj] * w[jj];
      }
    }
    #pragma unroll
    for (int j = 0; j < 8; ++j) *(f4*)&bu[tr * 8 + j][4 * tc] = acc[j];
  }
  __syncthreads();

  // rescan with true init; overwrite bu with ys (x component)
  if (t < Kn) {
    const int p = t >> 1;
    const float A  = fmaxf(Ad[p], 0.0f);
    const float st = 1.0f / (1.0f + expf(-steps[p]));
    float m11, m12, m21, m22;
    make_M(A, st, m11, m12, m21, m22);
    const float f1 = m11 * st, f2 = m21 * st;
    float2 init = carry[((size_t)b * NC + chunk) * Kn + t];
    float z = init.x, x = init.y;
    #pragma unroll 8
    for (int s = 0; s < Sc; ++s) {
      float bv = bu[s][t];
      float zn = fmaf(m11, z, fmaf(m12, x, f1 * bv));
      float xn = fmaf(m21, z, fmaf(m22, x, f2 * bv));
      z = zn; x = xn;
      bu[s][t] = x;
    }
  }
  __syncthreads();

  // out GEMM: out[row][h] = sum_k ys[row][k]*WcT[k][h] + u[row][h]*D[h]
  {
    const f4* __restrict__ W4 = (const f4*)WcT;
    f4 acc[8];
    #pragma unroll
    for (int j = 0; j < 8; ++j) acc[j] = (f4)0.f;
    #pragma unroll 4
    for (int k4 = 0; k4 < Kn; k4 += 4) {
      f4 w[4];
      #pragma unroll
      for (int jj = 0; jj < 4; ++jj) w[jj] = W4[(k4 + jj) * (Hn / 4) + tc];
      #pragma unroll
      for (int j = 0; j < 8; ++j) {
        f4 yv = *(const f4*)&bu[tr * 8 + j][k4];
        #pragma unroll
        for (int jj = 0; jj < 4; ++jj) acc[j] += yv[jj] * w[jj];
      }
    }
    const f4 dv = ((const f4*)Dv)[tc];
    f4* __restrict__ out4 = (f4*)out;
    #pragma unroll
    for (int j = 0; j < 8; ++j) {
      int r = tr * 8 + j;
      f4 uv = *(const f4*)&us[r][4 * tc];
      out4[(row0 + r) * (Hn / 4) + tc] = acc[j] + uv * dv;
    }
  }
}

extern "C" void kernel_launch(void* const* d_in, const int* in_sizes, int n_in,
                              void* d_out, int out_size, void* d_ws, size_t ws_size,
                              hipStream_t stream) {
  const float* u     = (const float*)d_in[0];
  const float* Ad    = (const float*)d_in[1];
  const float* Br    = (const float*)d_in[2];
  const float* Bi    = (const float*)d_in[3];
  const float* Cr    = (const float*)d_in[4];
  const float* Ci    = (const float*)d_in[5];
  const float* Dv    = (const float*)d_in[6];
  const float* steps = (const float*)d_in[7];
  float* out = (float*)d_out;

  // workspace: carry [B*NC*Kn float2 = 512KB] | WbT [64KB] | WcT [64KB]
  float2* carry = (float2*)d_ws;
  float*  WbT   = (float*)(carry + (size_t)Bn * NC * Kn);
  float*  WcT   = WbT + Hn * Kn;

  const int nblk = Bn * NC;   // 512

  prep_kernel <<<2 * Hn * Kn / 256, 256, 0, stream>>>(Br, Bi, Cr, Ci, WbT, WcT);
  k1_bu_scan  <<<nblk, 256, 0, stream>>>(u, WbT, Ad, steps, carry);
  k2_propagate<<<Bn * Kn / 4, 256, 0, stream>>>(Ad, steps, carry);
  k3_scan_out <<<nblk, 256, 0, stream>>>(u, WbT, WcT, Dv, Ad, steps, carry, out);
}

// Round 4
// 43.615 us; speedup vs baseline: 4.0197x; 1.4506x over previous
//
#include <hip/hip_runtime.h>
#include <cmath>

// Problem constants: B=4, L=8192, H=128, P=64
constexpr int Bn = 4;
constexpr int Ln = 8192;
constexpr int Hn = 128;
constexpr int Pn = 64;
constexpr int Kn = 128;         // 2*P interleaved (k = 2p+c)
constexpr int Sc = 64;          // chunk length (rows per block)
constexpr int NC = Ln / Sc;     // 128 chunks per batch

typedef float f4 __attribute__((ext_vector_type(4)));
typedef float f32x4 __attribute__((ext_vector_type(4)));
typedef unsigned short us8 __attribute__((ext_vector_type(8)));
typedef unsigned short us4 __attribute__((ext_vector_type(4)));
typedef __bf16 bf16x8 __attribute__((ext_vector_type(8)));

__device__ __forceinline__ unsigned short f2bf(float f) {
  unsigned u = __builtin_bit_cast(unsigned, f);
  u += 0x7fffu + ((u >> 16) & 1u);        // round-to-nearest-even
  return (unsigned short)(u >> 16);
}

__device__ __forceinline__ f32x4 mfma_bf16(us8 a, us8 b, f32x4 c) {
  return __builtin_amdgcn_mfma_f32_16x16x32_bf16(
      __builtin_bit_cast(bf16x8, a), __builtin_bit_cast(bf16x8, b), c, 0, 0, 0);
}

__device__ __forceinline__ void make_M(float A, float st,
    float& m11, float& m12, float& m21, float& m22) {
  float s2A   = st * st * A;
  float schur = 1.0f / (1.0f + s2A);
  m11 = 1.0f - s2A * schur;
  m12 = -st * A * schur;
  m21 = st * schur;
  m22 = schur;
}

// ------------------------------------------------- prep: weights -> bf16, output-major
// WbN[n][h] = (n&1 ? Bi : Br)[n>>1][h]    (Bu[r][n] = sum_h u[r][h]*WbN[n][h])
// WcH[h][k] = (k&1 ? -Ci : Cr)[h][k>>1]   (out[r][h] = sum_k ys[r][k]*WcH[h][k])
__global__ __launch_bounds__(256) void prep_kernel(
    const float* __restrict__ Br, const float* __restrict__ Bi,
    const float* __restrict__ Cr, const float* __restrict__ Ci,
    unsigned short* __restrict__ WbN, unsigned short* __restrict__ WcH) {
  int tid = blockIdx.x * 256 + threadIdx.x;
  if (tid < Hn * Kn) {
    int n = tid >> 7, h = tid & 127, p = n >> 1;
    float v = (n & 1) ? Bi[p * Hn + h] : Br[p * Hn + h];
    WbN[tid] = f2bf(v);
  } else {
    int i = tid - Hn * Kn;
    int h = i >> 7, k = i & 127, p = k >> 1;
    float v = (k & 1) ? -Ci[h * Pn + p] : Cr[h * Pn + p];
    WcH[i] = f2bf(v);
  }
}

// ------------------------------------------------- 64x128 @ 128x128 MFMA tile
// usb: swizzled bf16 A-tile in LDS ([64][128], byte ^= (row&7)<<4)
// W:   bf16 weights in global, output-col-major [128 cols][128 k] (k contiguous)
// outlds: f32 [64][128] in LDS
__device__ __forceinline__ void gemm_tile(
    const unsigned short* __restrict__ usb,
    const unsigned short* __restrict__ W,
    float* __restrict__ outlds, int t) {
  const int wave = t >> 6, lane = t & 63;
  const int arow = wave * 16 + (lane & 15);   // A: row = lane&15 (+16/wave)
  const int kg = lane >> 4;                   // k-group: k = kk*32 + kg*8 + j

  us8 afr[4];
  #pragma unroll
  for (int kk = 0; kk < 4; ++kk)
    afr[kk] = *(const us8*)((const char*)usb +
        ((arow * 256 + kk * 64 + kg * 16) ^ ((arow & 7) << 4)));

  #pragma unroll
  for (int nt = 0; nt < 8; ++nt) {
    const int n = nt * 16 + (lane & 15);      // B: col = lane&15 (+16/tile)
    f32x4 acc = {0.f, 0.f, 0.f, 0.f};
    #pragma unroll
    for (int kk = 0; kk < 4; ++kk) {
      us8 bfr = *(const us8*)(W + n * Kn + kk * 32 + kg * 8);
      acc = mfma_bf16(afr[kk], bfr, acc);
    }
    const int crow = wave * 16 + (lane >> 4) * 4;  // C/D: verified m89 mapping
    const int ccol = nt * 16 + (lane & 15);
    #pragma unroll
    for (int r = 0; r < 4; ++r)
      outlds[(crow + r) * Kn + ccol] = acc[r];
  }
}

// ------------------------------------------------- K1: Bu MFMA (LDS) + local chunk scan -> carry
__global__ __launch_bounds__(256) void k1_bu_scan(
    const float* __restrict__ u, const unsigned short* __restrict__ WbN,
    const float* __restrict__ Ad, const float* __restrict__ steps,
    float2* __restrict__ carry) {
  __shared__ unsigned short usb[Sc * Hn];
  __shared__ float bu[Sc * Kn];
  const int t = threadIdx.x;
  const int b = blockIdx.x >> 7;
  const int chunk = blockIdx.x & (NC - 1);
  const size_t row0 = (size_t)b * Ln + (size_t)chunk * Sc;

  // stage u tile -> bf16 LDS (swizzled)
  const f4* __restrict__ u4 = (const f4*)(u + row0 * Hn);
  #pragma unroll
  for (int i = 0; i < 8; ++i) {
    int idx = t + i * 256;
    f4 v = u4[idx];
    int row = idx >> 5, c0 = (idx & 31) * 4;
    us4 pk = {f2bf(v[0]), f2bf(v[1]), f2bf(v[2]), f2bf(v[3])};
    *(us4*)((char*)usb + ((row * 256 + c0 * 2) ^ ((row & 7) << 4))) = pk;
  }
  __syncthreads();

  gemm_tile(usb, WbN, bu, t);
  __syncthreads();

  // local scan over Sc steps (threads 0..127, one per k-series)
  if (t < Kn) {
    const int p = t >> 1;
    const float A  = fmaxf(Ad[p], 0.0f);
    const float st = 1.0f / (1.0f + expf(-steps[p]));
    float m11, m12, m21, m22;
    make_M(A, st, m11, m12, m21, m22);
    const float f1 = m11 * st, f2 = m21 * st;
    float z = 0.f, x = 0.f;
    #pragma unroll 8
    for (int s = 0; s < Sc; ++s) {
      float bv = bu[s * Kn + t];
      float zn = fmaf(m11, z, fmaf(m12, x, f1 * bv));
      float xn = fmaf(m21, z, fmaf(m22, x, f2 * bv));
      z = zn; x = xn;
    }
    carry[((size_t)b * NC + chunk) * Kn + t] = make_float2(z, x);
  }
}

// ------------------------------------------------- K2: wave-parallel carry propagation
__global__ __launch_bounds__(256) void k2_propagate(
    const float* __restrict__ Ad, const float* __restrict__ steps,
    float2* __restrict__ carry) {
  const int wave = threadIdx.x >> 6;
  const int lane = threadIdx.x & 63;
  const int series = blockIdx.x * 4 + wave;        // 0..511
  const int b = series >> 7;
  const int k = series & 127;
  const int p = k >> 1;

  const float A  = fmaxf(Ad[p], 0.0f);
  const float st = 1.0f / (1.0f + expf(-steps[p]));
  float m11, m12, m21, m22;
  make_M(A, st, m11, m12, m21, m22);
  // A_c = M^Sc (Sc=64 -> 6 squarings)
  float ca = m11, cb = m12, cc = m21, cd = m22;
  #pragma unroll
  for (int i = 0; i < 6; ++i) {
    float na = ca * ca + cb * cc;
    float nb = ca * cb + cb * cd;
    float nc = cc * ca + cd * cc;
    float nd = cc * cb + cd * cd;
    ca = na; cb = nb; cc = nc; cd = nd;
  }

  const size_t base = ((size_t)b * NC) * Kn + k;
  float2 c0 = carry[base + (size_t)(2 * lane) * Kn];
  float2 c1 = carry[base + (size_t)(2 * lane + 1) * Kn];

  // lane-local fold: chunk 2i then 2i+1
  float Aa = ca * ca + cb * cc;
  float Ab = ca * cb + cb * cd;
  float Ac = cc * ca + cd * cc;
  float Adl = cc * cb + cd * cd;
  float bz = ca * c0.x + cb * c0.y + c1.x;
  float bx = cc * c0.x + cd * c0.y + c1.y;

  // inclusive shfl-scan of affine maps
  #pragma unroll
  for (int d = 1; d < 64; d <<= 1) {
    float oAa = __shfl_up(Aa, d), oAb = __shfl_up(Ab, d);
    float oAc = __shfl_up(Ac, d), oAd = __shfl_up(Adl, d);
    float obz = __shfl_up(bz, d), obx = __shfl_up(bx, d);
    if (lane >= d) {
      float nbz = Aa * obz + Ab * obx + bz;
      float nbx = Ac * obz + Adl * obx + bx;
      float nAa = Aa * oAa + Ab * oAc;
      float nAb = Aa * oAb + Ab * oAd;
      float nAc = Ac * oAa + Adl * oAc;
      float nAd = Ac * oAb + Adl * oAd;
      Aa = nAa; Ab = nAb; Ac = nAc; Adl = nAd; bz = nbz; bx = nbx;
    }
  }

  // exclusive prefix (init state = 0, so only b-component matters)
  float ebz = __shfl_up(bz, 1);
  float ebx = __shfl_up(bx, 1);
  if (lane == 0) { ebz = 0.f; ebx = 0.f; }

  carry[base + (size_t)(2 * lane) * Kn]     = make_float2(ebz, ebx);
  carry[base + (size_t)(2 * lane + 1) * Kn] =
      make_float2(ca * ebz + cb * ebx + c0.x, cc * ebz + cd * ebx + c0.y);
}

// ------------------------------------------------- K3: Bu MFMA + rescan + out MFMA + residual
__global__ __launch_bounds__(256) void k3_scan_out(
    const float* __restrict__ u, const unsigned short* __restrict__ WbN,
    const unsigned short* __restrict__ WcH, const float* __restrict__ Dv,
    const float* __restrict__ Ad, const float* __restrict__ steps,
    const float2* __restrict__ carry, float* __restrict__ out) {
  __shared__ unsigned short usb[Sc * Hn];
  __shared__ float bu[Sc * Kn];
  const int t = threadIdx.x;
  const int b = blockIdx.x >> 7;
  const int chunk = blockIdx.x & (NC - 1);
  const size_t row0 = (size_t)b * Ln + (size_t)chunk * Sc;

  const f4* __restrict__ u4 = (const f4*)(u + row0 * Hn);
  #pragma unroll
  for (int i = 0; i < 8; ++i) {
    int idx = t + i * 256;
    f4 v = u4[idx];
    int row = idx >> 5, c0 = (idx & 31) * 4;
    us4 pk = {f2bf(v[0]), f2bf(v[1]), f2bf(v[2]), f2bf(v[3])};
    *(us4*)((char*)usb + ((row * 256 + c0 * 2) ^ ((row & 7) << 4))) = pk;
  }
  __syncthreads();

  gemm_tile(usb, WbN, bu, t);
  __syncthreads();

  // rescan with true init; overwrite bu with ys (x component)
  if (t < Kn) {
    const int p = t >> 1;
    const float A  = fmaxf(Ad[p], 0.0f);
    const float st = 1.0f / (1.0f + expf(-steps[p]));
    float m11, m12, m21, m22;
    make_M(A, st, m11, m12, m21, m22);
    const float f1 = m11 * st, f2 = m21 * st;
    float2 init = carry[((size_t)b * NC + chunk) * Kn + t];
    float z = init.x, x = init.y;
    #pragma unroll 8
    for (int s = 0; s < Sc; ++s) {
      float bv = bu[s * Kn + t];
      float zn = fmaf(m11, z, fmaf(m12, x, f1 * bv));
      float xn = fmaf(m21, z, fmaf(m22, x, f2 * bv));
      z = zn; x = xn;
      bu[s * Kn + t] = x;
    }
  }
  __syncthreads();

  // convert ys (f32, bu) -> bf16 swizzled A-tile (usb)
  #pragma unroll
  for (int i = 0; i < 8; ++i) {
    int idx = t + i * 256;
    int row = idx >> 5, c0 = (idx & 31) * 4;
    f4 v = *(const f4*)&bu[row * Kn + c0];
    us4 pk = {f2bf(v[0]), f2bf(v[1]), f2bf(v[2]), f2bf(v[3])};
    *(us4*)((char*)usb + ((row * 256 + c0 * 2) ^ ((row & 7) << 4))) = pk;
  }
  __syncthreads();

  gemm_tile(usb, WcH, bu, t);   // bu <- ys @ WcT  (each wave overwrites its own rows)
  __syncthreads();

  // residual + coalesced store
  const f4* __restrict__ Dv4 = (const f4*)Dv;
  f4* __restrict__ out4 = (f4*)out;
  #pragma unroll
  for (int i = 0; i < 8; ++i) {
    int idx = t + i * 256;
    int row = idx >> 5, c0 = (idx & 31) * 4;
    f4 acc = *(const f4*)&bu[row * Kn + c0];
    f4 uv = u4[idx];
    f4 dv = Dv4[idx & 31];
    f4 res;
    #pragma unroll
    for (int j = 0; j < 4; ++j) res[j] = fmaf(uv[j], dv[j], acc[j]);
    out4[row0 * (Hn / 4) + idx] = res;
  }
}

extern "C" void kernel_launch(void* const* d_in, const int* in_sizes, int n_in,
                              void* d_out, int out_size, void* d_ws, size_t ws_size,
                              hipStream_t stream) {
  const float* u     = (const float*)d_in[0];
  const float* Ad    = (const float*)d_in[1];
  const float* Br    = (const float*)d_in[2];
  const float* Bi    = (const float*)d_in[3];
  const float* Cr    = (const float*)d_in[4];
  const float* Ci    = (const float*)d_in[5];
  const float* Dv    = (const float*)d_in[6];
  const float* steps = (const float*)d_in[7];
  float* out = (float*)d_out;

  // workspace: carry [B*NC*Kn float2 = 512KB] | WbN bf16 [32KB] | WcH bf16 [32KB]
  float2* carry = (float2*)d_ws;
  unsigned short* WbN = (unsigned short*)(carry + (size_t)Bn * NC * Kn);
  unsigned short* WcH = WbN + Hn * Kn;

  const int nblk = Bn * NC;   // 512

  prep_kernel <<<2 * Hn * Kn / 256, 256, 0, stream>>>(Br, Bi, Cr, Ci, WbN, WcH);
  k1_bu_scan  <<<nblk, 256, 0, stream>>>(u, WbN, Ad, steps, carry);
  k2_propagate<<<Bn * Kn / 4, 256, 0, stream>>>(Ad, steps, carry);
  k3_scan_out <<<nblk, 256, 0, stream>>>(u, WbN, WcH, Dv, Ad, steps, carry, out);
}